// Round 6
// baseline (1623.463 us; speedup 1.0000x reference)
//
#include <hip/hip_runtime.h>

// SKA3D: x [B=2, C=64, D=64, H=64, W=64] fp32; w [B=2, G=8, 27, D, H, W] fp32
// out[b,c,d,h,w] = sum_k x[b,c,(d+di)%64,(h+hi)%64,(w+wi)%64] * w[b,c/8,k,d,h,w]
//
// R6 = R5 (4-wave block, 2 ch/wave, 4-slot d-ring, raw barrier + counted vmcnt)
//  + halo reads via ds_read_b128 (R5's scalar b32 halos were an 8-way bank
//    conflict: wl residues {3,7,..,31} x 4 identical row-groups -> 8 banks)
//  + wk loads interleaved into compute: 9-tap chunk issued right after the
//    di-phase that retires those taps -> first-used taps get ~2/3-compute lead
//  + nontemporal out stores (out never re-read; stop evicting x/wk from L2/L3)
//  + __launch_bounds__(256,3): pin VGPR<=170 so 3 blocks/CU (12 waves) resident
//
// Per-wave per-iter VMEM order: stage(3), wk(9), wk(9), wk(9), stores(2).
// [A] vmcnt(29) drains my stage(d+1) (newer: 27 wk + 2 stores = 29). [B]
// s_barrier -> slot d+1 globally ready AND nobody still reads slot (d+2)&3.

#define ND 64
#define NH 64
#define NW 64
#define HW 4096
#define DHW 262144

typedef const __attribute__((address_space(1))) unsigned int* gp_as1;
typedef __attribute__((address_space(3))) unsigned int* lp_as3;
typedef float f32x4 __attribute__((ext_vector_type(4)));

__global__ __launch_bounds__(256, 3) void ska3d_kernel(const float* __restrict__ x,
                                                       const float* __restrict__ w,
                                                       float* __restrict__ out) {
    __shared__ float lds[4][8][6][NW];     // [slot][c][r][w] 48 KB

    const int tid  = threadIdx.x;          // 0..255
    const int lane = tid & 63;
    const int wv   = tid >> 6;             // wave id 0..3
    const int w0   = (lane & 15) * 4;      // w strip start
    const int hl   = lane >> 4;            // 0..3
    const int c0   = wv * 2;               // this wave's channels

    const int bid = blockIdx.x;
    const int dc  = bid & 7;               // d-chunk (8 planes)
    const int ht  = (bid >> 3) & 15;       // h-tile (4 rows)
    const int g   = (bid >> 7) & 7;
    const int b   = bid >> 10;

    const int d0 = dc * 8;
    const int h0 = ht * 4;
    const int h  = h0 + hl;

    const float* xb = x + (size_t)(b * 64 + g * 8) * DHW;
    const float* wb = w + (size_t)(b * 8 + g) * 27 * DHW + h * NW + w0;
    float* ob = out + (size_t)(b * 64 + g * 8 + c0) * DHW + h * NW + w0;

    const int wlb = (w0 + 60) & 63;        // aligned b128 holding x[w0-1] in .w
    const int wrb = (w0 + 4) & 63;         // aligned b128 holding x[w0+4] in .x

    // stage plane p: 768 16B-units, 256 threads -> 3 ops/thread
#define STAGE(p) do {                                                          \
        const int slot_ = (p) & 3;                                             \
        const int dd_   = (p) & 63;                                            \
        _Pragma("unroll")                                                      \
        for (int i_ = 0; i_ < 3; ++i_) {                                       \
            const int fid = i_ * 256 + tid;    /* 0..767 */                    \
            const int c_  = fid / 96;                                          \
            const int rm_ = fid - c_ * 96;                                     \
            const int r_  = rm_ >> 4;          /* 0..5 */                      \
            const int ws_ = rm_ & 15;          /* 0..15 */                     \
            const int hh_ = (h0 - 1 + r_) & 63;                                \
            const float* gsrc = xb + (size_t)c_ * DHW + dd_ * HW + hh_ * NW + ws_ * 4; \
            __builtin_amdgcn_global_load_lds((gp_as1)gsrc,                     \
                (lp_as3)&lds[slot_][c_][r_][ws_ * 4], 16, 0, 0);               \
        }                                                                      \
    } while (0)

    // load 9 w-taps [kb0, kb0+9) for plane dp
#define LOADW9(dp, kb0) do {                                                   \
        const float* wp_ = wb + (size_t)(dp) * HW;                             \
        _Pragma("unroll")                                                      \
        for (int k_ = 0; k_ < 9; ++k_)                                         \
            wk[(kb0) + k_] = *(const float4*)(wp_ + (size_t)((kb0) + k_) * DHW); \
    } while (0)

    // one di-plane of compute: 3 hi x 2 channels, all-b128 LDS reads
#define PHASE(d, di) do {                                                      \
        const int slot = ((d) + (di)) & 3;                                     \
        _Pragma("unroll")                                                      \
        for (int hi = -1; hi <= 1; ++hi) {                                     \
            const int r  = hl + hi + 1;            /* 0..5 */                  \
            const int kb = ((di) + 1) * 9 + (hi + 1) * 3;                      \
            _Pragma("unroll")                                                  \
            for (int cc = 0; cc < 2; ++cc) {                                   \
                const float* row = &lds[slot][c0 + cc][r][0];                  \
                const float4 xm4 = *(const float4*)(row + wlb);                \
                const float4 xv  = *(const float4*)(row + w0);                 \
                const float4 xp4 = *(const float4*)(row + wrb);                \
                const float4 wa = wk[kb], wm = wk[kb + 1], wc = wk[kb + 2];    \
                acc[cc][0] += wa.x * xm4.w;  acc[cc][1] += wa.y * xv.x;        \
                acc[cc][2] += wa.z * xv.y;   acc[cc][3] += wa.w * xv.z;        \
                acc[cc][0] += wm.x * xv.x;   acc[cc][1] += wm.y * xv.y;        \
                acc[cc][2] += wm.z * xv.z;   acc[cc][3] += wm.w * xv.w;        \
                acc[cc][0] += wc.x * xv.y;   acc[cc][1] += wc.y * xv.z;        \
                acc[cc][2] += wc.z * xv.w;   acc[cc][3] += wc.w * xp4.x;       \
            }                                                                  \
        }                                                                      \
    } while (0)

    float4 wk[27];

    // prologue: planes d0-1, d0, d0+1 staged; wk(d0) loaded; full drain
    STAGE(d0 - 1);
    STAGE(d0);
    STAGE(d0 + 1);
    LOADW9(d0, 0); LOADW9(d0, 9); LOADW9(d0, 18);
    asm volatile("s_waitcnt vmcnt(0)" ::: "memory");

#pragma unroll 1
    for (int i = 0; i < 8; ++i) {
        const int d = d0 + i;

        // [A] drain my stage(d+1); newer ops = 27 wk + 2 stores = 29
        asm volatile("s_waitcnt vmcnt(29)" ::: "memory");
        // [B] all waves' stage(d+1) done; all waves done reading slot (d+2)&3
        asm volatile("s_barrier" ::: "memory");

        // [C] prefetch plane d+2 into slot (d+2)&3 (disjoint from d-1,d,d+1)
        if (i < 7) STAGE(d + 2);

        float acc[2][4];
#pragma unroll
        for (int cc = 0; cc < 2; ++cc)
            acc[cc][0] = acc[cc][1] = acc[cc][2] = acc[cc][3] = 0.f;

        // [D] compute d, refilling each 9-tap wk chunk right after its last use
        PHASE(d, -1);
        if (i < 7) LOADW9(d + 1, 0);
        PHASE(d, 0);
        if (i < 7) LOADW9(d + 1, 9);
        PHASE(d, 1);
        if (i < 7) LOADW9(d + 1, 18);

        // [E] nontemporal stores (out is never re-read)
#pragma unroll
        for (int cc = 0; cc < 2; ++cc) {
            f32x4 v;
            v.x = acc[cc][0]; v.y = acc[cc][1]; v.z = acc[cc][2]; v.w = acc[cc][3];
            __builtin_nontemporal_store(v,
                (f32x4*)(ob + (size_t)cc * DHW + (size_t)d * HW));
        }
    }
}

extern "C" void kernel_launch(void* const* d_in, const int* in_sizes, int n_in,
                              void* d_out, int out_size, void* d_ws, size_t ws_size,
                              hipStream_t stream) {
    const float* x = (const float*)d_in[0];
    const float* w = (const float*)d_in[1];
    float* out = (float*)d_out;
    // grid: b(2) x g(8) x h-tiles(16) x d-chunks(8) = 2048 blocks of 256
    dim3 grid(2048);
    dim3 block(256);
    hipLaunchKernelGGL(ska3d_kernel, grid, block, 0, stream, x, w, out);
}

// Round 7
// 823.285 us; speedup vs baseline: 1.9719x; 1.9719x over previous
//
#include <hip/hip_runtime.h>

// SKA3D: x [B=2, C=64, D=64, H=64, W=64] fp32; w [B=2, G=8, 27, D, H, W] fp32
// out[b,c,d,h,w] = sum_k x[b,c,(d+di)%64,(h+hi)%64,(w+wi)%64] * w[b,c/8,k,d,h,w]
//
// R7 = R6 minus the spill: __launch_bounds__(256,2) (NOT 3 — capping VGPR at
// 170 spilled wk[27] (108 VGPR) to scratch: 6.2 GB spill traffic, 9.5x slower).
// Keeps from R6:
//  - halo reads via ds_read_b128 (conflict-free, vs scalar b32 8-way conflict)
//  - wk loads interleaved into compute (9-tap chunk reloaded right after its
//    phase retires it -> ~2/3-compute of HBM lead, no extra live range)
//  - nontemporal out stores (out never re-read; don't evict x/wk from L2/L3)
// Sync skeleton from R5: 4-wave block, 2 ch/wave, 4-slot d-ring LDS (48 KB),
// raw s_barrier + counted vmcnt, STAGE after barrier (WAR-safe by ordering).
//
// Per-wave per-iter VMEM order: stage(3), wk(9), wk(9), wk(9), stores(2).
// [A] vmcnt(29) drains my stage(d+1) (newer: 27 wk + 2 stores = 29). [B]
// s_barrier -> slot d+1 globally ready AND nobody still reads slot (d+2)&3.

#define ND 64
#define NH 64
#define NW 64
#define HW 4096
#define DHW 262144

typedef const __attribute__((address_space(1))) unsigned int* gp_as1;
typedef __attribute__((address_space(3))) unsigned int* lp_as3;
typedef float f32x4 __attribute__((ext_vector_type(4)));

__global__ __launch_bounds__(256, 2) void ska3d_kernel(const float* __restrict__ x,
                                                       const float* __restrict__ w,
                                                       float* __restrict__ out) {
    __shared__ float lds[4][8][6][NW];     // [slot][c][r][w] 48 KB

    const int tid  = threadIdx.x;          // 0..255
    const int lane = tid & 63;
    const int wv   = tid >> 6;             // wave id 0..3
    const int w0   = (lane & 15) * 4;      // w strip start
    const int hl   = lane >> 4;            // 0..3
    const int c0   = wv * 2;               // this wave's channels

    const int bid = blockIdx.x;
    const int dc  = bid & 7;               // d-chunk (8 planes)
    const int ht  = (bid >> 3) & 15;       // h-tile (4 rows)
    const int g   = (bid >> 7) & 7;
    const int b   = bid >> 10;

    const int d0 = dc * 8;
    const int h0 = ht * 4;
    const int h  = h0 + hl;

    const float* xb = x + (size_t)(b * 64 + g * 8) * DHW;
    const float* wb = w + (size_t)(b * 8 + g) * 27 * DHW + h * NW + w0;
    float* ob = out + (size_t)(b * 64 + g * 8 + c0) * DHW + h * NW + w0;

    const int wlb = (w0 + 60) & 63;        // aligned b128 holding x[w0-1] in .w
    const int wrb = (w0 + 4) & 63;         // aligned b128 holding x[w0+4] in .x

    // stage plane p: 768 16B-units, 256 threads -> 3 ops/thread
#define STAGE(p) do {                                                          \
        const int slot_ = (p) & 3;                                             \
        const int dd_   = (p) & 63;                                            \
        _Pragma("unroll")                                                      \
        for (int i_ = 0; i_ < 3; ++i_) {                                       \
            const int fid = i_ * 256 + tid;    /* 0..767 */                    \
            const int c_  = fid / 96;                                          \
            const int rm_ = fid - c_ * 96;                                     \
            const int r_  = rm_ >> 4;          /* 0..5 */                      \
            const int ws_ = rm_ & 15;          /* 0..15 */                     \
            const int hh_ = (h0 - 1 + r_) & 63;                                \
            const float* gsrc = xb + (size_t)c_ * DHW + dd_ * HW + hh_ * NW + ws_ * 4; \
            __builtin_amdgcn_global_load_lds((gp_as1)gsrc,                     \
                (lp_as3)&lds[slot_][c_][r_][ws_ * 4], 16, 0, 0);               \
        }                                                                      \
    } while (0)

    // load 9 w-taps [kb0, kb0+9) for plane dp
#define LOADW9(dp, kb0) do {                                                   \
        const float* wp_ = wb + (size_t)(dp) * HW;                             \
        _Pragma("unroll")                                                      \
        for (int k_ = 0; k_ < 9; ++k_)                                         \
            wk[(kb0) + k_] = *(const float4*)(wp_ + (size_t)((kb0) + k_) * DHW); \
    } while (0)

    // one di-plane of compute: 3 hi x 2 channels, all-b128 LDS reads
#define PHASE(d, di) do {                                                      \
        const int slot = ((d) + (di)) & 3;                                     \
        _Pragma("unroll")                                                      \
        for (int hi = -1; hi <= 1; ++hi) {                                     \
            const int r  = hl + hi + 1;            /* 0..5 */                  \
            const int kb = ((di) + 1) * 9 + (hi + 1) * 3;                      \
            _Pragma("unroll")                                                  \
            for (int cc = 0; cc < 2; ++cc) {                                   \
                const float* row = &lds[slot][c0 + cc][r][0];                  \
                const float4 xm4 = *(const float4*)(row + wlb);                \
                const float4 xv  = *(const float4*)(row + w0);                 \
                const float4 xp4 = *(const float4*)(row + wrb);                \
                const float4 wa = wk[kb], wm = wk[kb + 1], wc = wk[kb + 2];    \
                acc[cc][0] += wa.x * xm4.w;  acc[cc][1] += wa.y * xv.x;        \
                acc[cc][2] += wa.z * xv.y;   acc[cc][3] += wa.w * xv.z;        \
                acc[cc][0] += wm.x * xv.x;   acc[cc][1] += wm.y * xv.y;        \
                acc[cc][2] += wm.z * xv.z;   acc[cc][3] += wm.w * xv.w;        \
                acc[cc][0] += wc.x * xv.y;   acc[cc][1] += wc.y * xv.z;        \
                acc[cc][2] += wc.z * xv.w;   acc[cc][3] += wc.w * xp4.x;       \
            }                                                                  \
        }                                                                      \
    } while (0)

    float4 wk[27];

    // prologue: planes d0-1, d0, d0+1 staged; wk(d0) loaded; full drain
    STAGE(d0 - 1);
    STAGE(d0);
    STAGE(d0 + 1);
    LOADW9(d0, 0); LOADW9(d0, 9); LOADW9(d0, 18);
    asm volatile("s_waitcnt vmcnt(0)" ::: "memory");

#pragma unroll 1
    for (int i = 0; i < 8; ++i) {
        const int d = d0 + i;

        // [A] drain my stage(d+1); newer ops = 27 wk + 2 stores = 29
        asm volatile("s_waitcnt vmcnt(29)" ::: "memory");
        // [B] all waves' stage(d+1) done; all waves done reading slot (d+2)&3
        asm volatile("s_barrier" ::: "memory");

        // [C] prefetch plane d+2 into slot (d+2)&3 (disjoint from d-1,d,d+1)
        if (i < 7) STAGE(d + 2);

        float acc[2][4];
#pragma unroll
        for (int cc = 0; cc < 2; ++cc)
            acc[cc][0] = acc[cc][1] = acc[cc][2] = acc[cc][3] = 0.f;

        // [D] compute d, refilling each 9-tap wk chunk right after its last use
        PHASE(d, -1);
        if (i < 7) LOADW9(d + 1, 0);
        PHASE(d, 0);
        if (i < 7) LOADW9(d + 1, 9);
        PHASE(d, 1);
        if (i < 7) LOADW9(d + 1, 18);

        // [E] nontemporal stores (out is never re-read)
#pragma unroll
        for (int cc = 0; cc < 2; ++cc) {
            f32x4 v;
            v.x = acc[cc][0]; v.y = acc[cc][1]; v.z = acc[cc][2]; v.w = acc[cc][3];
            __builtin_nontemporal_store(v,
                (f32x4*)(ob + (size_t)cc * DHW + (size_t)d * HW));
        }
    }
}

extern "C" void kernel_launch(void* const* d_in, const int* in_sizes, int n_in,
                              void* d_out, int out_size, void* d_ws, size_t ws_size,
                              hipStream_t stream) {
    const float* x = (const float*)d_in[0];
    const float* w = (const float*)d_in[1];
    float* out = (float*)d_out;
    // grid: b(2) x g(8) x h-tiles(16) x d-chunks(8) = 2048 blocks of 256
    dim3 grid(2048);
    dim3 block(256);
    hipLaunchKernelGGL(ska3d_kernel, grid, block, 0, stream, x, w, out);
}

// Round 8
// 219.321 us; speedup vs baseline: 7.4022x; 3.7538x over previous
//
#include <hip/hip_runtime.h>

// SKA3D: x [B=2, C=64, D=64, H=64, W=64] fp32; w [B=2, G=8, 27, D, H, W] fp32
// out[b,c,d,h,w] = sum_k x[b,c,(d+di)%64,(h+hi)%64,(w+wi)%64] * w[b,c/8,k,d,h,w]
//
// R8: per-wave shape = R5's proven no-spill form (2 ch x 4 rows x strip-4,
// wk[27] float4 loaded whole at iteration end). Block level reworked:
//  - 512-thread blocks (8 waves), h-tile = 8 rows: x staging 1.25x (was 1.5x)
//  - LDS rows of 72 floats: [pad3, x63, x0..x63, x0..x3] -> halo reads are
//    wrap-free constant-offset scalars (fusable to ds_read2_b32), no wrap VALU
//  - replica columns staged by pointing the PER-LANE global source at the
//    wrapped data (LDS dest stays linear, as global_load_lds requires)
//  - nontemporal output stores; XCD swizzle (dc-adjacent blocks share 2/10
//    staged planes -> same-XCD L2 hits)
//  - occupancy: amdgpu_waves_per_eu(1,2): aim 2 waves/EU (256-VGPR budget),
//    relax to 1 instead of spilling (R6/R7 lesson: allocator spills wk[27]
//    if it targets 4 waves/EU)
// Sync: 4-slot d-ring, raw s_barrier + counted vmcnt. Per-wave per-iter VMEM:
// stage(<=3) + stores(2) + wk(27); at [A], ops newer than my stage = 29.

#define ND 64
#define NH 64
#define NW 64
#define HW 4096
#define DHW 262144
#define ROWF 72                      // floats per LDS row (3 pad + 1 + 64 + 4)

typedef const __attribute__((address_space(1))) unsigned int* gp_as1;
typedef __attribute__((address_space(3))) unsigned int* lp_as3;
typedef float f32x4 __attribute__((ext_vector_type(4)));

__global__ __launch_bounds__(512)
__attribute__((amdgpu_waves_per_eu(1, 2)))
void ska3d_kernel(const float* __restrict__ x,
                  const float* __restrict__ w,
                  float* __restrict__ out) {
    __shared__ float lds[4][8][10][ROWF];   // [slot][c][r][w'] 90 KB

    const int tid  = threadIdx.x;           // 0..511
    const int lane = tid & 63;
    const int wv   = tid >> 6;              // wave id 0..7
    const int j    = lane & 15;             // w strip index
    const int w0   = j * 4;                 // w strip start
    const int hl   = lane >> 4;             // 0..3
    const int c0   = wv & 6;                // channel pair: 0,0,2,2,4,4,6,6
    const int rh   = (wv & 1) * 4;          // row half: 0 or 4

    // XCD swizzle: consecutive sbid <- bids with equal bid%8 (same XCD)
    const int bid  = blockIdx.x;            // 0..1023
    const int sbid = (bid & 7) * 128 + (bid >> 3);
    const int dc   = sbid & 7;              // d-chunk (8 planes)
    const int ht   = (sbid >> 3) & 7;       // h-tile (8 rows)
    const int g    = (sbid >> 6) & 7;
    const int b    = sbid >> 9;

    const int d0 = dc * 8;
    const int h0 = ht * 8;
    const int h  = h0 + rh + hl;            // this lane's output row

    const float* xb = x + (size_t)(b * 64 + g * 8) * DHW;
    const float* wb = w + (size_t)(b * 8 + g) * 27 * DHW + h * NW + w0;
    float* ob = out + (size_t)(b * 64 + g * 8 + c0) * DHW + h * NW + w0;

    // stage plane p: 8c x 10r x 18 units (16B each) = 1440 units, 512 threads
    // unit u: u==0 -> global x[hh][60..63] (x63 lands at row idx 3)
    //         u==17 -> global x[hh][0..3]  (x0..3 replica at idx 68..71)
    //         else  -> global x[hh][(u-1)*4 ..]
#define STAGE(p) do {                                                          \
        const int slot_ = (p) & 3;                                             \
        const int dd_   = (p) & 63;                                            \
        _Pragma("unroll")                                                      \
        for (int i_ = 0; i_ < 3; ++i_) {                                       \
            const int fid = i_ * 512 + tid;      /* 0..1535 */                 \
            if (fid < 1440) {                                                  \
                const int c_  = fid / 180;                                     \
                const int rm_ = fid - c_ * 180;                                \
                const int r_  = rm_ / 18;        /* 0..9 */                    \
                const int u_  = rm_ - r_ * 18;   /* 0..17 */                   \
                const int hh_ = (h0 - 1 + r_) & 63;                            \
                const int sw_ = (u_ == 0) ? 60 : ((u_ == 17) ? 0 : (u_ - 1) * 4); \
                const float* gsrc = xb + (size_t)c_ * DHW + dd_ * HW + hh_ * NW + sw_; \
                __builtin_amdgcn_global_load_lds((gp_as1)gsrc,                 \
                    (lp_as3)&lds[slot_][c_][r_][u_ * 4], 16, 0, 0);            \
            }                                                                  \
        }                                                                      \
    } while (0)

#define LOADW(dp) do {                                                         \
        const float* wp_ = wb + (size_t)(dp) * HW;                             \
        _Pragma("unroll")                                                      \
        for (int k_ = 0; k_ < 27; ++k_)                                        \
            wk[k_] = *(const float4*)(wp_ + (size_t)k_ * DHW);                 \
    } while (0)

    float4 wk[27];

    // prologue: planes d0-1, d0, d0+1; wk(d0); full drain, then loop barrier
    STAGE(d0 - 1);
    STAGE(d0);
    STAGE(d0 + 1);
    LOADW(d0);
    asm volatile("s_waitcnt vmcnt(0)" ::: "memory");

#pragma unroll 1
    for (int i = 0; i < 8; ++i) {
        const int d = d0 + i;

        // [A] drain my stage(d+1); ops newer than it: 2 stores + 27 wk = 29
        asm volatile("s_waitcnt vmcnt(29)" ::: "memory");
        // [B] all waves' stage(d+1) done; nobody still reads slot (d+2)&3
        asm volatile("s_barrier" ::: "memory");

        // [C] prefetch plane d+2
        if (i < 7) STAGE(d + 2);

        // [D] compute plane d
        float acc[2][4];
#pragma unroll
        for (int cc = 0; cc < 2; ++cc)
            acc[cc][0] = acc[cc][1] = acc[cc][2] = acc[cc][3] = 0.f;

#pragma unroll
        for (int di = -1; di <= 1; ++di) {
            const int slot = (d + di) & 3;
#pragma unroll
            for (int hi = -1; hi <= 1; ++hi) {
                const int r  = rh + hl + hi + 1;      // 0..9
                const int kb = (di + 1) * 9 + (hi + 1) * 3;
#pragma unroll
                for (int cc = 0; cc < 2; ++cc) {
                    const float* row = &lds[slot][c0 + cc][r][0];
                    const float  xm = row[3 + w0];               // x[w0-1]
                    const float4 xv = *(const float4*)(row + 4 + w0);
                    const float  xp = row[8 + w0];               // x[w0+4]
                    const float4 wa = wk[kb], wm = wk[kb + 1], wc = wk[kb + 2];
                    acc[cc][0] += wa.x * xm;    acc[cc][1] += wa.y * xv.x;
                    acc[cc][2] += wa.z * xv.y;  acc[cc][3] += wa.w * xv.z;
                    acc[cc][0] += wm.x * xv.x;  acc[cc][1] += wm.y * xv.y;
                    acc[cc][2] += wm.z * xv.z;  acc[cc][3] += wm.w * xv.w;
                    acc[cc][0] += wc.x * xv.y;  acc[cc][1] += wc.y * xv.z;
                    acc[cc][2] += wc.z * xv.w;  acc[cc][3] += wc.w * xp;
                }
            }
        }

#pragma unroll
        for (int cc = 0; cc < 2; ++cc) {
            f32x4 v;
            v.x = acc[cc][0]; v.y = acc[cc][1]; v.z = acc[cc][2]; v.w = acc[cc][3];
            __builtin_nontemporal_store(v,
                (f32x4*)(ob + (size_t)cc * DHW + (size_t)d * HW));
        }

        // [E] wk(d+1) for next iteration (R5 position: whole, at loop end)
        if (i < 7) LOADW(d + 1);
    }
}

extern "C" void kernel_launch(void* const* d_in, const int* in_sizes, int n_in,
                              void* d_out, int out_size, void* d_ws, size_t ws_size,
                              hipStream_t stream) {
    const float* x = (const float*)d_in[0];
    const float* w = (const float*)d_in[1];
    float* out = (float*)d_out;
    // grid: b(2) x g(8) x h-tiles(8) x d-chunks(8) = 1024 blocks of 512
    dim3 grid(1024);
    dim3 block(512);
    hipLaunchKernelGGL(ska3d_kernel, grid, block, 0, stream, x, w, out);
}

// Round 9
// 156.282 us; speedup vs baseline: 10.3881x; 1.4034x over previous
//
#include <hip/hip_runtime.h>

// SKA3D: x [B=2, C=64, D=64, H=64, W=64] fp32; w [B=2, G=8, 27, D, H, W] fp32
// out[b,c,d,h,w] = sum_k x[b,c,(d+di)%64,(h+hi)%64,(w+wi)%64] * w[b,c/8,k,d,h,w]
//
// R9 = R5's proven skeleton (4-wave block, 2 ch/wave, 4-slot d-ring, 48 KB LDS,
// raw s_barrier + counted vmcnt, wk[27] loaded whole at loop end) with the LDS
// data path cut to 1/3:
//  - ONLY the aligned b128 xv is read from LDS (18 reads/wave-iter, conflict-
//    free). W-halos come from neighbor lanes via DPP row_ror on the VALU pipe:
//      x[w0-1] = lane(j-1)&15's xv.w  -> row_ror:1  (0x121)
//      x[w0+4] = lane(j+1)&15's xv.x  -> row_ror:15 (0x12F)
//    (R5's scalar b32 halos were 8-way bank-conflicted: ~88us/CU of LDS pipe.)
//  - nontemporal out stores (never re-read; don't evict x/w streams)
//  - amdgpu_waves_per_eu(2,3): allocator targets 3 waves/EU (170 VGPR) but
//    degrades to 2 (256 VGPR) instead of spilling (R6/R7 spill lesson)
//
// Per-wave per-iter VMEM order: stage(3), stores(2), wk(27).
// [A] vmcnt(29) drains my stage(d+1) (newer: 2 stores + 27 wk = 29).
// [B] s_barrier -> slot d+1 globally ready AND nobody still reads slot (d+2)&3.

#define ND 64
#define NH 64
#define NW 64
#define HW 4096
#define DHW 262144

typedef const __attribute__((address_space(1))) unsigned int* gp_as1;
typedef __attribute__((address_space(3))) unsigned int* lp_as3;
typedef float f32x4 __attribute__((ext_vector_type(4)));

__device__ __forceinline__ float dpp_prev(float v) {   // lane j <- lane (j-1)&15
    int i = __builtin_bit_cast(int, v);
    i = __builtin_amdgcn_update_dpp(i, i, 0x121, 0xF, 0xF, true);  // row_ror:1
    return __builtin_bit_cast(float, i);
}
__device__ __forceinline__ float dpp_next(float v) {   // lane j <- lane (j+1)&15
    int i = __builtin_bit_cast(int, v);
    i = __builtin_amdgcn_update_dpp(i, i, 0x12F, 0xF, 0xF, true);  // row_ror:15
    return __builtin_bit_cast(float, i);
}

__global__ __launch_bounds__(256)
__attribute__((amdgpu_waves_per_eu(2, 3)))
void ska3d_kernel(const float* __restrict__ x,
                  const float* __restrict__ w,
                  float* __restrict__ out) {
    __shared__ float lds[4][8][6][NW];     // [slot][c][r][w] 48 KB

    const int tid  = threadIdx.x;          // 0..255
    const int lane = tid & 63;
    const int wv   = tid >> 6;             // wave id 0..3
    const int w0   = (lane & 15) * 4;      // w strip start
    const int hl   = lane >> 4;            // 0..3
    const int c0   = wv * 2;               // this wave's channels

    const int bid = blockIdx.x;
    const int dc  = bid & 7;               // d-chunk (8 planes)
    const int ht  = (bid >> 3) & 15;       // h-tile (4 rows)
    const int g   = (bid >> 7) & 7;
    const int b   = bid >> 10;

    const int d0 = dc * 8;
    const int h0 = ht * 4;
    const int h  = h0 + hl;

    const float* xb = x + (size_t)(b * 64 + g * 8) * DHW;
    const float* wb = w + (size_t)(b * 8 + g) * 27 * DHW + h * NW + w0;
    float* ob = out + (size_t)(b * 64 + g * 8 + c0) * DHW + h * NW + w0;

    // stage plane p: 768 16B-units, 256 threads -> 3 ops/thread
#define STAGE(p) do {                                                          \
        const int slot_ = (p) & 3;                                             \
        const int dd_   = (p) & 63;                                            \
        _Pragma("unroll")                                                      \
        for (int i_ = 0; i_ < 3; ++i_) {                                       \
            const int fid = i_ * 256 + tid;    /* 0..767 */                    \
            const int c_  = fid / 96;                                          \
            const int rm_ = fid - c_ * 96;                                     \
            const int r_  = rm_ >> 4;          /* 0..5 */                      \
            const int ws_ = rm_ & 15;          /* 0..15 */                     \
            const int hh_ = (h0 - 1 + r_) & 63;                                \
            const float* gsrc = xb + (size_t)c_ * DHW + dd_ * HW + hh_ * NW + ws_ * 4; \
            __builtin_amdgcn_global_load_lds((gp_as1)gsrc,                     \
                (lp_as3)&lds[slot_][c_][r_][ws_ * 4], 16, 0, 0);               \
        }                                                                      \
    } while (0)

#define LOADW(dp) do {                                                         \
        const float* wp_ = wb + (size_t)(dp) * HW;                             \
        _Pragma("unroll")                                                      \
        for (int k_ = 0; k_ < 27; ++k_)                                        \
            wk[k_] = *(const float4*)(wp_ + (size_t)k_ * DHW);                 \
    } while (0)

    float4 wk[27];

    // prologue: planes d0-1, d0, d0+1 staged; wk(d0) loaded; full drain
    STAGE(d0 - 1);
    STAGE(d0);
    STAGE(d0 + 1);
    LOADW(d0);
    asm volatile("s_waitcnt vmcnt(0)" ::: "memory");

#pragma unroll 1
    for (int i = 0; i < 8; ++i) {
        const int d = d0 + i;

        // [A] drain my stage(d+1); newer ops = 2 stores + 27 wk = 29
        asm volatile("s_waitcnt vmcnt(29)" ::: "memory");
        // [B] all waves' stage(d+1) done; all waves done reading slot (d+2)&3
        asm volatile("s_barrier" ::: "memory");

        // [C] prefetch plane d+2 into slot (d+2)&3 (disjoint from d-1,d,d+1)
        if (i < 7) STAGE(d + 2);

        // [D] compute plane d: one b128 LDS read per (di,hi,cc); halos via DPP
        float acc[2][4];
#pragma unroll
        for (int cc = 0; cc < 2; ++cc)
            acc[cc][0] = acc[cc][1] = acc[cc][2] = acc[cc][3] = 0.f;

#pragma unroll
        for (int di = -1; di <= 1; ++di) {
            const int slot = (d + di) & 3;
#pragma unroll
            for (int hi = -1; hi <= 1; ++hi) {
                const int r  = hl + hi + 1;            // 0..5
                const int kb = (di + 1) * 9 + (hi + 1) * 3;
#pragma unroll
                for (int cc = 0; cc < 2; ++cc) {
                    const float* row = &lds[slot][c0 + cc][r][0];
                    const float4 xv = *(const float4*)(row + w0);
                    const float  xm = dpp_prev(xv.w);   // x[w0-1] (circular)
                    const float  xp = dpp_next(xv.x);   // x[w0+4] (circular)
                    const float4 wa = wk[kb], wm = wk[kb + 1], wc = wk[kb + 2];
                    acc[cc][0] += wa.x * xm;    acc[cc][1] += wa.y * xv.x;
                    acc[cc][2] += wa.z * xv.y;  acc[cc][3] += wa.w * xv.z;
                    acc[cc][0] += wm.x * xv.x;  acc[cc][1] += wm.y * xv.y;
                    acc[cc][2] += wm.z * xv.z;  acc[cc][3] += wm.w * xv.w;
                    acc[cc][0] += wc.x * xv.y;  acc[cc][1] += wc.y * xv.z;
                    acc[cc][2] += wc.z * xv.w;  acc[cc][3] += wc.w * xp;
                }
            }
        }

#pragma unroll
        for (int cc = 0; cc < 2; ++cc) {
            f32x4 v;
            v.x = acc[cc][0]; v.y = acc[cc][1]; v.z = acc[cc][2]; v.w = acc[cc][3];
            __builtin_nontemporal_store(v,
                (f32x4*)(ob + (size_t)cc * DHW + (size_t)d * HW));
        }

        // [E] wk(d+1) for next iteration (whole, at loop end — proven shape)
        if (i < 7) LOADW(d + 1);
    }
}

extern "C" void kernel_launch(void* const* d_in, const int* in_sizes, int n_in,
                              void* d_out, int out_size, void* d_ws, size_t ws_size,
                              hipStream_t stream) {
    const float* x = (const float*)d_in[0];
    const float* w = (const float*)d_in[1];
    float* out = (float*)d_out;
    // grid: b(2) x g(8) x h-tiles(16) x d-chunks(8) = 2048 blocks of 256
    dim3 grid(2048);
    dim3 block(256);
    hipLaunchKernelGGL(ska3d_kernel, grid, block, 0, stream, x, w, out);
}